// Round 10
// baseline (1224.812 us; speedup 1.0000x reference)
//
#include <hip/hip_runtime.h>
#include <hip/hip_bf16.h>

#define N_NODES 100000
#define N_PAD   100096      // 782 * 128, whole MFMA tiles past N_NODES
#define N_EDGES 1600000
#define OUT_CH  40

#define BSHIFT  6           // 64 nodes per bucket
#define BNODES  64
#define NBUCK   1563        // ceil(N_NODES / 64); covers nodes 0..100031
#define CAPB    1408        // edge capacity per bucket (mean 1024, +12 sigma)
#define EPB     16          // edges per thread in bucket_scatter

typedef unsigned short ushort_t;
typedef unsigned int uint_t;
typedef __attribute__((ext_vector_type(8))) short short8;   // 8 bf16 (4 VGPR)
typedef __attribute__((ext_vector_type(4))) float floatx4;  // MFMA C/D

__device__ inline float blo(uint_t u) { union { uint_t i; float f; } t; t.i = u << 16; return t.f; }
__device__ inline float bhi(uint_t u) { union { uint_t i; float f; } t; t.i = u & 0xffff0000u; return t.f; }
__device__ inline ushort_t f2b(float f) {
    __hip_bfloat16 h = __float2bfloat16(f);
    return *reinterpret_cast<ushort_t*>(&h);
}
__device__ inline uint_t pack2(float a, float b) {
    return (uint_t)f2b(a) | ((uint_t)f2b(b) << 16);
}

// ---------------------------------------------------------------------------
// f32 -> bf16 conversion, 8 elems/thread. Block 0 also zeroes the bucket
// cursors (stream order makes them ready before bucket_scatter).
// ---------------------------------------------------------------------------
__global__ __launch_bounds__(256) void convert_kernel(
    const float* __restrict__ in, ushort_t* __restrict__ out, int n8,
    int* __restrict__ gcur)
{
    if (blockIdx.x == 0) {
        for (int k = threadIdx.x; k < 2048; k += 256) gcur[k] = 0;
    }
    int i = blockIdx.x * 256 + threadIdx.x;
    if (i >= n8) return;
    const float4 a = *reinterpret_cast<const float4*>(in + (size_t)i * 8);
    const float4 b = *reinterpret_cast<const float4*>(in + (size_t)i * 8 + 4);
    uint4 o;
    o.x = pack2(a.x, a.y);
    o.y = pack2(a.z, a.w);
    o.z = pack2(b.x, b.y);
    o.w = pack2(b.z, b.w);
    *reinterpret_cast<uint4*>(out + (size_t)i * 8) = o;
}

// ---------------------------------------------------------------------------
// Weight pack into MFMA B-fragment layout (bf16).
// Frag (nt, kc): lane l holds W[k = kc*32 + (l>>4)*8 + j][col = nt*16 + (l&15)],
// j = 0..7, packed as uint4. Bases (frag units): W1l=0, W1r=512, W2l=1024,
// W2r=1408 (layer-2 cols padded 40->48 with zeros).
// ---------------------------------------------------------------------------
__global__ __launch_bounds__(256) void pack_kernel(
    const float* __restrict__ W1l, const float* __restrict__ W1r,
    const float* __restrict__ W2l, const float* __restrict__ W2r,
    uint4* __restrict__ wp)
{
    int i = blockIdx.x * 256 + threadIdx.x;
    if (i >= 1792) return;
    const float* W; int NC; int off;
    if (i < 512)       { W = W1l; NC = 64; off = i; }
    else if (i < 1024) { W = W1r; NC = 64; off = i - 512; }
    else if (i < 1408) { W = W2l; NC = 40; off = i - 1024; }
    else               { W = W2r; NC = 40; off = i - 1408; }
    int l   = off & 63;
    int kc  = (off >> 6) & 1;
    int nt  = off >> 7;
    int k0  = kc * 32 + ((l >> 4) * 8);
    int col = nt * 16 + (l & 15);
    float v[8];
#pragma unroll
    for (int j = 0; j < 8; ++j)
        v[j] = (col < NC) ? W[(k0 + j) * NC + col] : 0.0f;
    uint4 o;
    o.x = pack2(v[0], v[1]);
    o.y = pack2(v[2], v[3]);
    o.z = pack2(v[4], v[5]);
    o.w = pack2(v[6], v[7]);
    wp[i] = o;
}

// ---------------------------------------------------------------------------
// Phase 1: partition edges into NBUCK dst-range buckets (dst>>BSHIFT).
// Randomness confined to LDS histogram atomics; global writes are
// per-(block,bucket) bursts of PACKED edges: src (17b) | local-dst << 25.
// ---------------------------------------------------------------------------
__global__ __launch_bounds__(256) void bucket_scatter(
    const int* __restrict__ src, const int* __restrict__ dst,
    int* __restrict__ gcur, uint_t* __restrict__ bbuf, int n)
{
    __shared__ int lcnt[NBUCK];
    __shared__ int lbase[NBUCK];
    for (int i = threadIdx.x; i < NBUCK; i += 256) lcnt[i] = 0;
    __syncthreads();

    int e0 = blockIdx.x * (256 * EPB) + threadIdx.x;
    int b[EPB], lp[EPB], s[EPB];
#pragma unroll
    for (int u = 0; u < EPB; ++u) {
        int e = e0 + u * 256;
        if (e < n) {
            int d = dst[e];
            s[u] = src[e];
            b[u] = d >> BSHIFT;
            lp[u] = atomicAdd(&lcnt[b[u]], 1);        // pos fits 24 bits
            lp[u] |= (d & (BNODES - 1)) << 24;        // local node in bits 24..29
        } else {
            b[u] = -1;
        }
    }
    __syncthreads();
    for (int i = threadIdx.x; i < NBUCK; i += 256) {
        int c = lcnt[i];
        lbase[i] = (c > 0) ? atomicAdd(&gcur[i], c) : 0;
    }
    __syncthreads();
#pragma unroll
    for (int u = 0; u < EPB; ++u) {
        if (b[u] >= 0) {
            int pos = lbase[b[u]] + (lp[u] & 0x00FFFFFF);
            uint_t ldst = ((uint_t)lp[u]) >> 24;
            if (pos < CAPB)
                bbuf[(size_t)b[u] * CAPB + pos] = (uint_t)s[u] | (ldst << 25);
        }
    }
}

// ---------------------------------------------------------------------------
// Edge-order accumulation: stream packed edges, gather 16B feat chunk,
// atomicAdd 8 f32 into a chunk-XOR-swizzled LDS sum tile. No CSR at all;
// perfect edge balance; gathers issue from the first iteration.
// Channel chunk cc of row ld lives at lmeanf[ld*64 + (cc ^ (ld&7))*8 ..].
// ---------------------------------------------------------------------------
__device__ inline void edge_accumulate(
    const ushort_t* __restrict__ feat, const uint_t* __restrict__ eb, int ne,
    float* lmeanf, int* ldeg, int wave, int lane)
{
    int g = lane >> 3, c = lane & 7;
    int j = wave * 8 + g;

    for (; j + 64 < ne; j += 128) {     // 2 independent gather chains
        uint_t p0 = eb[j];
        uint_t p1 = eb[j + 64];
        int ld0 = (int)(p0 >> 25), s0 = (int)(p0 & 0x01FFFFFF);
        int ld1 = (int)(p1 >> 25), s1 = (int)(p1 & 0x01FFFFFF);
        uint4 v0 = *reinterpret_cast<const uint4*>(feat + (size_t)s0 * 64 + c * 8);
        uint4 v1 = *reinterpret_cast<const uint4*>(feat + (size_t)s1 * 64 + c * 8);
        float* a0 = &lmeanf[ld0 * 64 + ((c ^ (ld0 & 7)) << 3)];
        atomicAdd(a0 + 0, blo(v0.x)); atomicAdd(a0 + 1, bhi(v0.x));
        atomicAdd(a0 + 2, blo(v0.y)); atomicAdd(a0 + 3, bhi(v0.y));
        atomicAdd(a0 + 4, blo(v0.z)); atomicAdd(a0 + 5, bhi(v0.z));
        atomicAdd(a0 + 6, blo(v0.w)); atomicAdd(a0 + 7, bhi(v0.w));
        float* a1 = &lmeanf[ld1 * 64 + ((c ^ (ld1 & 7)) << 3)];
        atomicAdd(a1 + 0, blo(v1.x)); atomicAdd(a1 + 1, bhi(v1.x));
        atomicAdd(a1 + 2, blo(v1.y)); atomicAdd(a1 + 3, bhi(v1.y));
        atomicAdd(a1 + 4, blo(v1.z)); atomicAdd(a1 + 5, bhi(v1.z));
        atomicAdd(a1 + 6, blo(v1.w)); atomicAdd(a1 + 7, bhi(v1.w));
        if (c == 0) { atomicAdd(&ldeg[ld0], 1); atomicAdd(&ldeg[ld1], 1); }
    }
    if (j < ne) {
        uint_t p = eb[j];
        int ld = (int)(p >> 25), s = (int)(p & 0x01FFFFFF);
        uint4 v = *reinterpret_cast<const uint4*>(feat + (size_t)s * 64 + c * 8);
        float* a = &lmeanf[ld * 64 + ((c ^ (ld & 7)) << 3)];
        atomicAdd(a + 0, blo(v.x)); atomicAdd(a + 1, bhi(v.x));
        atomicAdd(a + 2, blo(v.y)); atomicAdd(a + 3, bhi(v.y));
        atomicAdd(a + 4, blo(v.z)); atomicAdd(a + 5, bhi(v.z));
        atomicAdd(a + 6, blo(v.w)); atomicAdd(a + 7, bhi(v.w));
        if (c == 0) atomicAdd(&ldeg[ld], 1);
    }
}

// Build the two A-fragments (K 0..31, 32..63) for row mrow from the swizzled
// f32 sum tile, scaled by inv.
__device__ inline void mean_frags(
    const float* lmeanf, int mrow, int q, float inv, short8& am0, short8& am1)
{
    const float* mp0 = &lmeanf[mrow * 64 + (((q)     ^ (mrow & 7)) << 3)];
    const float* mp1 = &lmeanf[mrow * 64 + (((q + 4) ^ (mrow & 7)) << 3)];
    uint4 u0, u1;
    u0.x = pack2(mp0[0] * inv, mp0[1] * inv);
    u0.y = pack2(mp0[2] * inv, mp0[3] * inv);
    u0.z = pack2(mp0[4] * inv, mp0[5] * inv);
    u0.w = pack2(mp0[6] * inv, mp0[7] * inv);
    u1.x = pack2(mp1[0] * inv, mp1[1] * inv);
    u1.y = pack2(mp1[2] * inv, mp1[3] * inv);
    u1.z = pack2(mp1[4] * inv, mp1[5] * inv);
    u1.w = pack2(mp1[6] * inv, mp1[7] * inv);
    am0 = *reinterpret_cast<short8*>(&u0);
    am1 = *reinterpret_cast<short8*>(&u1);
}

// ---------------------------------------------------------------------------
// Fused per-bucket layer 1: edge-accumulate -> mean -> MFMA -> relu -> h1b.
// 512 threads / 8 waves; dense: wave w handles M-tile w>>1, nt pair (w&1)*2.
// ---------------------------------------------------------------------------
__global__ __launch_bounds__(512) void agg_dense1(
    const ushort_t* __restrict__ xb, const int* __restrict__ gcur,
    const uint_t* __restrict__ bbuf, const uint4* __restrict__ wp,
    const float* __restrict__ bias, ushort_t* __restrict__ h1b)
{
    __shared__ float lmeanf[BNODES * 64];   // 16 KB
    __shared__ int   ldeg[BNODES];

    int b = blockIdx.x, tid = threadIdx.x;
    int wave = tid >> 6, lane = tid & 63;

    for (int i = tid; i < BNODES * 64; i += 512) lmeanf[i] = 0.0f;
    if (tid < BNODES) ldeg[tid] = 0;
    __syncthreads();

    int ne = gcur[b]; if (ne > CAPB) ne = CAPB;
    edge_accumulate(xb, bbuf + (size_t)b * CAPB, ne, lmeanf, ldeg, wave, lane);
    __syncthreads();

    int q = lane >> 4, c16 = lane & 15;
    int mt  = wave >> 1;            // M-tile 0..3
    int nt0 = (wave & 1) * 2;       // nt pair
    int mrow = mt * 16 + c16;
    int node0 = b << BSHIFT;

    float inv = 1.0f / fmaxf((float)ldeg[mrow], 1.0f);
    short8 am0, am1;
    mean_frags(lmeanf, mrow, q, inv, am0, am1);
    const ushort_t* sr = xb + (size_t)(node0 + mrow) * 64 + q * 8;
    short8 as0 = *reinterpret_cast<const short8*>(sr);
    short8 as1 = *reinterpret_cast<const short8*>(sr + 32);

#pragma unroll
    for (int t = 0; t < 2; ++t) {
        int nt = nt0 + t;
        short8 bl0 = *reinterpret_cast<const short8*>(&wp[nt * 128 + lane]);
        short8 bl1 = *reinterpret_cast<const short8*>(&wp[nt * 128 + 64 + lane]);
        short8 br0 = *reinterpret_cast<const short8*>(&wp[512 + nt * 128 + lane]);
        short8 br1 = *reinterpret_cast<const short8*>(&wp[512 + nt * 128 + 64 + lane]);
        float bv = bias[nt * 16 + c16];
        floatx4 a = (floatx4){bv, bv, bv, bv};
        a = __builtin_amdgcn_mfma_f32_16x16x32_bf16(am0, bl0, a, 0, 0, 0);
        a = __builtin_amdgcn_mfma_f32_16x16x32_bf16(am1, bl1, a, 0, 0, 0);
        a = __builtin_amdgcn_mfma_f32_16x16x32_bf16(as0, br0, a, 0, 0, 0);
        a = __builtin_amdgcn_mfma_f32_16x16x32_bf16(as1, br1, a, 0, 0, 0);
#pragma unroll
        for (int rr = 0; rr < 4; ++rr) {
            int node = node0 + mt * 16 + q * 4 + rr;
            h1b[(size_t)node * 64 + nt * 16 + c16] = f2b(fmaxf(a[rr], 0.0f));
        }
    }
}

// ---------------------------------------------------------------------------
// Fused per-bucket layer 2: edge-accumulate(h1) -> mean -> MFMA -> log_softmax.
// Dense: waves 0..3 each own one M-tile (all 3 nt, softmax needs the row).
// ---------------------------------------------------------------------------
__global__ __launch_bounds__(512) void agg_dense2(
    const ushort_t* __restrict__ h1b, const int* __restrict__ gcur,
    const uint_t* __restrict__ bbuf, const uint4* __restrict__ wp,
    const float* __restrict__ bias, float* __restrict__ out)
{
    __shared__ float lmeanf[BNODES * 64];
    __shared__ int   ldeg[BNODES];

    int b = blockIdx.x, tid = threadIdx.x;
    int wave = tid >> 6, lane = tid & 63;

    for (int i = tid; i < BNODES * 64; i += 512) lmeanf[i] = 0.0f;
    if (tid < BNODES) ldeg[tid] = 0;
    __syncthreads();

    int ne = gcur[b]; if (ne > CAPB) ne = CAPB;
    edge_accumulate(h1b, bbuf + (size_t)b * CAPB, ne, lmeanf, ldeg, wave, lane);
    __syncthreads();

    if (wave >= 4) return;

    int q = lane >> 4, c16 = lane & 15;
    int mt = wave;
    int mrow = mt * 16 + c16;
    int node0 = b << BSHIFT;
    bool v2ok = c16 < 8;    // tile 2 real cols: 32..39

    float inv = 1.0f / fmaxf((float)ldeg[mrow], 1.0f);
    short8 am0, am1;
    mean_frags(lmeanf, mrow, q, inv, am0, am1);
    const ushort_t* sr = h1b + (size_t)(node0 + mrow) * 64 + q * 8;
    short8 as0 = *reinterpret_cast<const short8*>(sr);
    short8 as1 = *reinterpret_cast<const short8*>(sr + 32);

    floatx4 av[3];
#pragma unroll
    for (int nt = 0; nt < 3; ++nt) {
        short8 bl0 = *reinterpret_cast<const short8*>(&wp[1024 + nt * 128 + lane]);
        short8 bl1 = *reinterpret_cast<const short8*>(&wp[1024 + nt * 128 + 64 + lane]);
        short8 br0 = *reinterpret_cast<const short8*>(&wp[1408 + nt * 128 + lane]);
        short8 br1 = *reinterpret_cast<const short8*>(&wp[1408 + nt * 128 + 64 + lane]);
        int col = nt * 16 + c16;
        float bv = (col < OUT_CH) ? bias[col] : 0.0f;
        floatx4 a = (floatx4){bv, bv, bv, bv};
        a = __builtin_amdgcn_mfma_f32_16x16x32_bf16(am0, bl0, a, 0, 0, 0);
        a = __builtin_amdgcn_mfma_f32_16x16x32_bf16(am1, bl1, a, 0, 0, 0);
        a = __builtin_amdgcn_mfma_f32_16x16x32_bf16(as0, br0, a, 0, 0, 0);
        a = __builtin_amdgcn_mfma_f32_16x16x32_bf16(as1, br1, a, 0, 0, 0);
        av[nt] = a;
    }

    // fused log_softmax per node; row lives in the 16-lane col group
    // (shfl_xor 1,2,4,8 stays within the group; q fixed).
#pragma unroll
    for (int rr = 0; rr < 4; ++rr) {
        float v0 = av[0][rr];
        float v1 = av[1][rr];
        float v2 = av[2][rr];
        float mx = fmaxf(fmaxf(v0, v1), v2ok ? v2 : -1e30f);
        mx = fmaxf(mx, __shfl_xor(mx, 1, 64));
        mx = fmaxf(mx, __shfl_xor(mx, 2, 64));
        mx = fmaxf(mx, __shfl_xor(mx, 4, 64));
        mx = fmaxf(mx, __shfl_xor(mx, 8, 64));
        float e = __expf(v0 - mx) + __expf(v1 - mx) + (v2ok ? __expf(v2 - mx) : 0.0f);
        e += __shfl_xor(e, 1, 64);
        e += __shfl_xor(e, 2, 64);
        e += __shfl_xor(e, 4, 64);
        e += __shfl_xor(e, 8, 64);
        float ls = __logf(e);
        int node = node0 + mt * 16 + q * 4 + rr;
        if (node < N_NODES) {
            out[(size_t)node * OUT_CH + c16]      = v0 - mx - ls;
            out[(size_t)node * OUT_CH + 16 + c16] = v1 - mx - ls;
            if (v2ok)
                out[(size_t)node * OUT_CH + 32 + c16] = v2 - mx - ls;
        }
    }
}

extern "C" void kernel_launch(void* const* d_in, const int* in_sizes, int n_in,
                              void* d_out, int out_size, void* d_ws, size_t ws_size,
                              hipStream_t stream)
{
    const float* x   = (const float*)d_in[0];
    const int*   ei  = (const int*)d_in[1];     // (2, N_EDGES) int32
    const float* W1l = (const float*)d_in[2];
    const float* W1r = (const float*)d_in[3];
    const float* b1  = (const float*)d_in[4];
    const float* W2l = (const float*)d_in[5];
    const float* W2r = (const float*)d_in[6];
    const float* b2  = (const float*)d_in[7];
    float* out = (float*)d_out;

    const int* src = ei;
    const int* dst = ei + N_EDGES;

    // workspace layout
    int* gcur       = (int*)d_ws;                         // [2048] bucket cursors
    uint4* wp       = (uint4*)(gcur + 2048);              // [1792] frags, 28KB
    uint_t* bbuf    = (uint_t*)(wp + 1792);               // [NBUCK*CAPB] packed edges ~8.8MB
    ushort_t* xb    = (ushort_t*)(bbuf + (size_t)NBUCK * CAPB);  // [N_PAD*64] bf16
    ushort_t* h1b   = xb + (size_t)N_PAD * 64;            // [N_PAD*64] bf16
    // total ~= 0.04 + 8.8 + 25.6 MB ~= 34.5 MB

    const int n8 = N_NODES * 64 / 8;

    convert_kernel<<<(n8 + 255) / 256, 256, 0, stream>>>(x, xb, n8, gcur);
    pack_kernel<<<7, 256, 0, stream>>>(W1l, W1r, W2l, W2r, wp);

    const int sblocks = (N_EDGES + 256 * EPB - 1) / (256 * EPB);
    bucket_scatter<<<sblocks, 256, 0, stream>>>(src, dst, gcur, bbuf, N_EDGES);

    agg_dense1<<<NBUCK, 512, 0, stream>>>(xb, gcur, bbuf, wp, b1, h1b);
    agg_dense2<<<NBUCK, 512, 0, stream>>>(h1b, gcur, bbuf, wp, b2, out);
}

// Round 11
// 161.190 us; speedup vs baseline: 7.5986x; 7.5986x over previous
//
#include <hip/hip_runtime.h>
#include <hip/hip_bf16.h>

#define N_NODES 100000
#define N_PAD   100096      // 782 * 128, whole MFMA tiles past N_NODES
#define N_EDGES 1600000
#define OUT_CH  40

#define BSHIFT  6           // 64 nodes per bucket
#define BNODES  64
#define NBUCK   1563        // ceil(N_NODES / 64); covers nodes 0..100031
#define CAPB    1408        // edge capacity per bucket (mean 1024, +12 sigma)
#define EPB     16          // edges per thread in bucket_scatter

typedef unsigned short ushort_t;
typedef unsigned int uint_t;
typedef __attribute__((ext_vector_type(8))) short short8;   // 8 bf16 (4 VGPR)
typedef __attribute__((ext_vector_type(4))) float floatx4;  // MFMA C/D

__device__ inline float blo(uint_t u) { union { uint_t i; float f; } t; t.i = u << 16; return t.f; }
__device__ inline float bhi(uint_t u) { union { uint_t i; float f; } t; t.i = u & 0xffff0000u; return t.f; }
__device__ inline ushort_t f2b(float f) {
    __hip_bfloat16 h = __float2bfloat16(f);
    return *reinterpret_cast<ushort_t*>(&h);
}
__device__ inline uint_t pack2(float a, float b) {
    return (uint_t)f2b(a) | ((uint_t)f2b(b) << 16);
}

// ---------------------------------------------------------------------------
// f32 -> bf16 conversion, 8 elems/thread. Block 0 also zeroes the bucket
// cursors + compact-CSR counter (ready before bucket_scatter in stream order).
// ---------------------------------------------------------------------------
__global__ __launch_bounds__(256) void convert_kernel(
    const float* __restrict__ in, ushort_t* __restrict__ out, int n8,
    int* __restrict__ gcur)
{
    if (blockIdx.x == 0) {
        for (int k = threadIdx.x; k < 2048; k += 256) gcur[k] = 0;
    }
    int i = blockIdx.x * 256 + threadIdx.x;
    if (i >= n8) return;
    const float4 a = *reinterpret_cast<const float4*>(in + (size_t)i * 8);
    const float4 b = *reinterpret_cast<const float4*>(in + (size_t)i * 8 + 4);
    uint4 o;
    o.x = pack2(a.x, a.y);
    o.y = pack2(a.z, a.w);
    o.z = pack2(b.x, b.y);
    o.w = pack2(b.z, b.w);
    *reinterpret_cast<uint4*>(out + (size_t)i * 8) = o;
}

// ---------------------------------------------------------------------------
// Weight pack into MFMA B-fragment layout (bf16).
// Frag (nt, kc): lane l holds W[k = kc*32 + (l>>4)*8 + j][col = nt*16 + (l&15)],
// j = 0..7, packed as uint4. Bases (frag units): W1l=0, W1r=512, W2l=1024,
// W2r=1408 (layer-2 cols padded 40->48 with zeros).
// ---------------------------------------------------------------------------
__global__ __launch_bounds__(256) void pack_kernel(
    const float* __restrict__ W1l, const float* __restrict__ W1r,
    const float* __restrict__ W2l, const float* __restrict__ W2r,
    uint4* __restrict__ wp)
{
    int i = blockIdx.x * 256 + threadIdx.x;
    if (i >= 1792) return;
    const float* W; int NC; int off;
    if (i < 512)       { W = W1l; NC = 64; off = i; }
    else if (i < 1024) { W = W1r; NC = 64; off = i - 512; }
    else if (i < 1408) { W = W2l; NC = 40; off = i - 1024; }
    else               { W = W2r; NC = 40; off = i - 1408; }
    int l   = off & 63;
    int kc  = (off >> 6) & 1;
    int nt  = off >> 7;
    int k0  = kc * 32 + ((l >> 4) * 8);
    int col = nt * 16 + (l & 15);
    float v[8];
#pragma unroll
    for (int j = 0; j < 8; ++j)
        v[j] = (col < NC) ? W[(k0 + j) * NC + col] : 0.0f;
    uint4 o;
    o.x = pack2(v[0], v[1]);
    o.y = pack2(v[2], v[3]);
    o.z = pack2(v[4], v[5]);
    o.w = pack2(v[6], v[7]);
    wp[i] = o;
}

// ---------------------------------------------------------------------------
// Phase 1: partition edges into NBUCK dst-range buckets (dst>>BSHIFT).
// Randomness confined to LDS histogram atomics; global writes are
// per-(block,bucket) bursts of PACKED edges: src (17b) | local-dst << 25.
// ---------------------------------------------------------------------------
__global__ __launch_bounds__(256) void bucket_scatter(
    const int* __restrict__ src, const int* __restrict__ dst,
    int* __restrict__ gcur, uint_t* __restrict__ bbuf, int n)
{
    __shared__ int lcnt[NBUCK];
    __shared__ int lbase[NBUCK];
    for (int i = threadIdx.x; i < NBUCK; i += 256) lcnt[i] = 0;
    __syncthreads();

    int e0 = blockIdx.x * (256 * EPB) + threadIdx.x;
    int b[EPB], lp[EPB], s[EPB];
#pragma unroll
    for (int u = 0; u < EPB; ++u) {
        int e = e0 + u * 256;
        if (e < n) {
            int d = dst[e];
            s[u] = src[e];
            b[u] = d >> BSHIFT;
            lp[u] = atomicAdd(&lcnt[b[u]], 1);        // pos fits 24 bits
            lp[u] |= (d & (BNODES - 1)) << 24;        // local node in bits 24..29
        } else {
            b[u] = -1;
        }
    }
    __syncthreads();
    for (int i = threadIdx.x; i < NBUCK; i += 256) {
        int c = lcnt[i];
        lbase[i] = (c > 0) ? atomicAdd(&gcur[i], c) : 0;
    }
    __syncthreads();
#pragma unroll
    for (int u = 0; u < EPB; ++u) {
        if (b[u] >= 0) {
            int pos = lbase[b[u]] + (lp[u] & 0x00FFFFFF);
            uint_t ldst = ((uint_t)lp[u]) >> 24;
            if (pos < CAPB)
                bbuf[(size_t)b[u] * CAPB + pos] = (uint_t)s[u] | (ldst << 25);
        }
    }
}

// ---------------------------------------------------------------------------
// Phase 2: one block per bucket. Build the bucket's COMPACT CSR in LDS
// (LDS atomics only), allocate the global segment with ONE atomicAdd, then
// dump row_start/deg/csr coalesced. Total global CSR = 6.4 MB (not 25.6).
// ---------------------------------------------------------------------------
__global__ __launch_bounds__(256) void csr_build(
    const int* __restrict__ gcur, const uint_t* __restrict__ bbuf,
    int* __restrict__ gctr, int* __restrict__ row_start,
    int* __restrict__ deg, int* __restrict__ csr)
{
    __shared__ uint_t spair[CAPB];
    __shared__ int    lcsr[CAPB];
    __shared__ int    ldeg[BNODES];
    __shared__ int    lstart[BNODES];
    __shared__ int    lcur[BNODES];
    __shared__ int    sbase;

    int b = blockIdx.x, tid = threadIdx.x;
    if (tid < BNODES) { ldeg[tid] = 0; lcur[tid] = 0; }
    __syncthreads();

    int ne = gcur[b];
    if (ne > CAPB) ne = CAPB;

    for (int i = tid; i < ne; i += 256) {
        uint_t p = bbuf[(size_t)b * CAPB + i];
        spair[i] = p;
        atomicAdd(&ldeg[p >> 25], 1);
    }
    __syncthreads();

    if (tid == 0) sbase = atomicAdd(gctr, ne);
    // single-wave exclusive scan over 64 degree counts
    if (tid >= 64 && tid < 128) {
        int l = tid - 64;
        int v = ldeg[l];
        int incl = v;
#pragma unroll
        for (int off = 1; off < 64; off <<= 1) {
            int t = __shfl_up(incl, off, 64);
            if (l >= off) incl += t;
        }
        lstart[l] = incl - v;
    }
    __syncthreads();

    for (int i = tid; i < ne; i += 256) {
        uint_t p = spair[i];
        int d = (int)(p >> 25);
        int pos = atomicAdd(&lcur[d], 1);
        lcsr[lstart[d] + pos] = (int)(p & 0x01FFFFFF);
    }
    __syncthreads();

    int node0 = b << BSHIFT;
    int lim = N_NODES - node0;
    if (lim > BNODES) lim = BNODES;
    if (tid < lim) {
        row_start[node0 + tid] = sbase + lstart[tid];
        deg[node0 + tid]       = ldeg[tid];
    }
    for (int i = tid; i < ne; i += 256) csr[sbase + i] = lcsr[i];
}

// ---------------------------------------------------------------------------
// Gather-mean (bf16 in/out). One wave per node (R6 structure: best measured
// fetch rate), compact CSR via row_start. 8 rows per VMEM instr:
// r = lane>>3 row, c = lane&7 16B channel chunk; up to 32 rows in flight.
// ---------------------------------------------------------------------------
__device__ inline void accum8(float* acc, uint4 v) {
    acc[0] += blo(v.x); acc[1] += bhi(v.x);
    acc[2] += blo(v.y); acc[3] += bhi(v.y);
    acc[4] += blo(v.z); acc[5] += bhi(v.z);
    acc[6] += blo(v.w); acc[7] += bhi(v.w);
}

__global__ __launch_bounds__(256) void agg_mean_kernel(
    const ushort_t* __restrict__ feat, const int* __restrict__ csr,
    const int* __restrict__ row_start, const int* __restrict__ deg,
    ushort_t* __restrict__ meanb)
{
    int wave = threadIdx.x >> 6;
    int lane = threadIdx.x & 63;
    int node = blockIdx.x * 4 + wave;       // N_NODES % 4 == 0

    int rs = row_start[node];
    int dg = deg[node];
    int r = lane >> 3;
    int c = lane & 7;

    float acc[8] = {0, 0, 0, 0, 0, 0, 0, 0};

    int j = 0;
    for (; j + 32 <= dg; j += 32) {
        int s0 = csr[rs + j + r];
        int s1 = csr[rs + j + 8 + r];
        int s2 = csr[rs + j + 16 + r];
        int s3 = csr[rs + j + 24 + r];
        uint4 v0 = *reinterpret_cast<const uint4*>(feat + (size_t)s0 * 64 + c * 8);
        uint4 v1 = *reinterpret_cast<const uint4*>(feat + (size_t)s1 * 64 + c * 8);
        uint4 v2 = *reinterpret_cast<const uint4*>(feat + (size_t)s2 * 64 + c * 8);
        uint4 v3 = *reinterpret_cast<const uint4*>(feat + (size_t)s3 * 64 + c * 8);
        accum8(acc, v0); accum8(acc, v1); accum8(acc, v2); accum8(acc, v3);
    }
    if (j + 16 <= dg) {
        int s0 = csr[rs + j + r];
        int s1 = csr[rs + j + 8 + r];
        uint4 v0 = *reinterpret_cast<const uint4*>(feat + (size_t)s0 * 64 + c * 8);
        uint4 v1 = *reinterpret_cast<const uint4*>(feat + (size_t)s1 * 64 + c * 8);
        accum8(acc, v0); accum8(acc, v1);
        j += 16;
    }
    if (j + 8 <= dg) {
        int s = csr[rs + j + r];
        uint4 v = *reinterpret_cast<const uint4*>(feat + (size_t)s * 64 + c * 8);
        accum8(acc, v);
        j += 8;
    }
    if (r < dg - j) {
        int s = csr[rs + j + r];
        uint4 v = *reinterpret_cast<const uint4*>(feat + (size_t)s * 64 + c * 8);
        accum8(acc, v);
    }

#pragma unroll
    for (int i = 0; i < 8; ++i) {
        acc[i] += __shfl_xor(acc[i], 8, 64);
        acc[i] += __shfl_xor(acc[i], 16, 64);
        acc[i] += __shfl_xor(acc[i], 32, 64);
    }

    if (r == 0) {
        float inv = 1.0f / fmaxf((float)dg, 1.0f);
        uint4 o;
        o.x = pack2(acc[0] * inv, acc[1] * inv);
        o.y = pack2(acc[2] * inv, acc[3] * inv);
        o.z = pack2(acc[4] * inv, acc[5] * inv);
        o.w = pack2(acc[6] * inv, acc[7] * inv);
        *reinterpret_cast<uint4*>(meanb + (size_t)node * 64 + c * 8) = o;
    }
}

// ---------------------------------------------------------------------------
// Dense layer 1 via MFMA: h1 = relu(mean@W1l + self@W1r + b1) -> bf16.
// 4 waves/block, 32 nodes/wave (2 M-tiles), 4 N-tiles of 16 outs.
// A-frag: lane l = feat[node(l&15)][kc*32 + (l>>4)*8 ..+7].
// D: row(node) = (l>>4)*4 + reg, col(out) = l&15.
// ---------------------------------------------------------------------------
__global__ __launch_bounds__(256) void dense1_mfma(
    const ushort_t* __restrict__ meanb, const ushort_t* __restrict__ selfb,
    const uint4* __restrict__ wp, const float* __restrict__ bias,
    ushort_t* __restrict__ h1b)
{
    int wave = threadIdx.x >> 6;
    int l    = threadIdx.x & 63;
    int nodebase0 = (blockIdx.x * 4 + wave) * 32;

    short8 bl[4][2], br[4][2];
#pragma unroll
    for (int nt = 0; nt < 4; ++nt)
#pragma unroll
        for (int kc = 0; kc < 2; ++kc) {
            bl[nt][kc] = *reinterpret_cast<const short8*>(&wp[nt * 128 + kc * 64 + l]);
            br[nt][kc] = *reinterpret_cast<const short8*>(&wp[512 + nt * 128 + kc * 64 + l]);
        }
    float bv[4];
#pragma unroll
    for (int nt = 0; nt < 4; ++nt) bv[nt] = bias[nt * 16 + (l & 15)];

    floatx4 acc[2][4];
#pragma unroll
    for (int m = 0; m < 2; ++m) {
        int nb = nodebase0 + m * 16;
        const ushort_t* mr = meanb + (size_t)(nb + (l & 15)) * 64 + ((l >> 4) * 8);
        const ushort_t* sr = selfb + (size_t)(nb + (l & 15)) * 64 + ((l >> 4) * 8);
        short8 am0 = *reinterpret_cast<const short8*>(mr);
        short8 am1 = *reinterpret_cast<const short8*>(mr + 32);
        short8 as0 = *reinterpret_cast<const short8*>(sr);
        short8 as1 = *reinterpret_cast<const short8*>(sr + 32);
#pragma unroll
        for (int nt = 0; nt < 4; ++nt) {
            floatx4 a = (floatx4){bv[nt], bv[nt], bv[nt], bv[nt]};
            a = __builtin_amdgcn_mfma_f32_16x16x32_bf16(am0, bl[nt][0], a, 0, 0, 0);
            a = __builtin_amdgcn_mfma_f32_16x16x32_bf16(am1, bl[nt][1], a, 0, 0, 0);
            a = __builtin_amdgcn_mfma_f32_16x16x32_bf16(as0, br[nt][0], a, 0, 0, 0);
            a = __builtin_amdgcn_mfma_f32_16x16x32_bf16(as1, br[nt][1], a, 0, 0, 0);
            acc[m][nt] = a;
        }
    }

#pragma unroll
    for (int m = 0; m < 2; ++m) {
        int nb = nodebase0 + m * 16;
#pragma unroll
        for (int nt = 0; nt < 4; ++nt)
#pragma unroll
            for (int r = 0; r < 4; ++r) {
                int node = nb + (l >> 4) * 4 + r;
                h1b[(size_t)node * 64 + nt * 16 + (l & 15)] =
                    f2b(fmaxf(acc[m][nt][r], 0.0f));
            }
    }
}

// ---------------------------------------------------------------------------
// Dense layer 2 via MFMA + fused log_softmax -> f32 out.
// 3 N-tiles (cols 0..47; 40 real, 8 zero-padded).
// ---------------------------------------------------------------------------
__global__ __launch_bounds__(256) void dense2_mfma(
    const ushort_t* __restrict__ meanb, const ushort_t* __restrict__ selfb,
    const uint4* __restrict__ wp, const float* __restrict__ bias,
    float* __restrict__ out)
{
    int wave = threadIdx.x >> 6;
    int l    = threadIdx.x & 63;
    int nodebase0 = (blockIdx.x * 4 + wave) * 32;
    int c16 = l & 15;
    bool v2ok = c16 < 8;    // tile 2 real cols: 32..39

    short8 bl[3][2], br[3][2];
#pragma unroll
    for (int nt = 0; nt < 3; ++nt)
#pragma unroll
        for (int kc = 0; kc < 2; ++kc) {
            bl[nt][kc] = *reinterpret_cast<const short8*>(&wp[1024 + nt * 128 + kc * 64 + l]);
            br[nt][kc] = *reinterpret_cast<const short8*>(&wp[1408 + nt * 128 + kc * 64 + l]);
        }
    float bv[3];
#pragma unroll
    for (int nt = 0; nt < 3; ++nt) {
        int col = nt * 16 + c16;
        bv[nt] = (col < OUT_CH) ? bias[col] : 0.0f;
    }

    floatx4 acc[2][3];
#pragma unroll
    for (int m = 0; m < 2; ++m) {
        int nb = nodebase0 + m * 16;
        const ushort_t* mr = meanb + (size_t)(nb + c16) * 64 + ((l >> 4) * 8);
        const ushort_t* sr = selfb + (size_t)(nb + c16) * 64 + ((l >> 4) * 8);
        short8 am0 = *reinterpret_cast<const short8*>(mr);
        short8 am1 = *reinterpret_cast<const short8*>(mr + 32);
        short8 as0 = *reinterpret_cast<const short8*>(sr);
        short8 as1 = *reinterpret_cast<const short8*>(sr + 32);
#pragma unroll
        for (int nt = 0; nt < 3; ++nt) {
            floatx4 a = (floatx4){bv[nt], bv[nt], bv[nt], bv[nt]};
            a = __builtin_amdgcn_mfma_f32_16x16x32_bf16(am0, bl[nt][0], a, 0, 0, 0);
            a = __builtin_amdgcn_mfma_f32_16x16x32_bf16(am1, bl[nt][1], a, 0, 0, 0);
            a = __builtin_amdgcn_mfma_f32_16x16x32_bf16(as0, br[nt][0], a, 0, 0, 0);
            a = __builtin_amdgcn_mfma_f32_16x16x32_bf16(as1, br[nt][1], a, 0, 0, 0);
            acc[m][nt] = a;
        }
    }

    // fused log_softmax per node (row lives in the 16-lane col group).
#pragma unroll
    for (int m = 0; m < 2; ++m) {
        int nb = nodebase0 + m * 16;
#pragma unroll
        for (int r = 0; r < 4; ++r) {
            float v0 = acc[m][0][r];
            float v1 = acc[m][1][r];
            float v2 = acc[m][2][r];
            float mx = fmaxf(fmaxf(v0, v1), v2ok ? v2 : -1e30f);
            mx = fmaxf(mx, __shfl_xor(mx, 1, 64));
            mx = fmaxf(mx, __shfl_xor(mx, 2, 64));
            mx = fmaxf(mx, __shfl_xor(mx, 4, 64));
            mx = fmaxf(mx, __shfl_xor(mx, 8, 64));
            float e = __expf(v0 - mx) + __expf(v1 - mx) + (v2ok ? __expf(v2 - mx) : 0.0f);
            e += __shfl_xor(e, 1, 64);
            e += __shfl_xor(e, 2, 64);
            e += __shfl_xor(e, 4, 64);
            e += __shfl_xor(e, 8, 64);
            float ls = __logf(e);
            int node = nb + (l >> 4) * 4 + r;
            if (node < N_NODES) {
                out[(size_t)node * OUT_CH + c16]      = v0 - mx - ls;
                out[(size_t)node * OUT_CH + 16 + c16] = v1 - mx - ls;
                if (v2ok)
                    out[(size_t)node * OUT_CH + 32 + c16] = v2 - mx - ls;
            }
        }
    }
}

extern "C" void kernel_launch(void* const* d_in, const int* in_sizes, int n_in,
                              void* d_out, int out_size, void* d_ws, size_t ws_size,
                              hipStream_t stream)
{
    const float* x   = (const float*)d_in[0];
    const int*   ei  = (const int*)d_in[1];     // (2, N_EDGES) int32
    const float* W1l = (const float*)d_in[2];
    const float* W1r = (const float*)d_in[3];
    const float* b1  = (const float*)d_in[4];
    const float* W2l = (const float*)d_in[5];
    const float* W2r = (const float*)d_in[6];
    const float* b2  = (const float*)d_in[7];
    float* out = (float*)d_out;

    const int* src = ei;
    const int* dst = ei + N_EDGES;

    // workspace layout
    int* gcur       = (int*)d_ws;                         // [2048] bucket cursors + gctr
    int* gctr       = gcur + 1600;                        // compact-CSR allocator (zeroed)
    uint4* wp       = (uint4*)(gcur + 2048);              // [1792] frags, 28KB
    uint_t* bbuf    = (uint_t*)(wp + 1792);               // [NBUCK*CAPB] packed edges ~8.8MB
    int* row_start  = (int*)(bbuf + (size_t)NBUCK * CAPB);  // [N]
    int* deg        = row_start + N_NODES;                // [N]
    int* csr        = deg + N_NODES;                      // [E] compact, 6.4MB
    ushort_t* xb    = (ushort_t*)(csr + N_EDGES);         // [N_PAD*64] bf16
    ushort_t* h1b   = xb + (size_t)N_PAD * 64;            // [N_PAD*64] bf16
    ushort_t* meanb = h1b + (size_t)N_PAD * 64;           // [N_PAD*64] bf16
    // total ~= 0.04 + 8.8 + 7.2 + 38.4 MB ~= 54.5 MB

    const int n8 = N_NODES * 64 / 8;

    convert_kernel<<<(n8 + 255) / 256, 256, 0, stream>>>(x, xb, n8, gcur);
    pack_kernel<<<7, 256, 0, stream>>>(W1l, W1r, W2l, W2r, wp);

    const int sblocks = (N_EDGES + 256 * EPB - 1) / (256 * EPB);
    bucket_scatter<<<sblocks, 256, 0, stream>>>(src, dst, gcur, bbuf, N_EDGES);
    csr_build<<<NBUCK, 256, 0, stream>>>(gcur, bbuf, gctr, row_start, deg, csr);

    agg_mean_kernel<<<N_NODES / 4, 256, 0, stream>>>(xb, csr, row_start, deg, meanb);
    dense1_mfma<<<N_PAD / 128, 256, 0, stream>>>(meanb, xb, wp, b1, h1b);

    agg_mean_kernel<<<N_NODES / 4, 256, 0, stream>>>(h1b, csr, row_start, deg, meanb);
    dense2_mfma<<<N_PAD / 128, 256, 0, stream>>>(meanb, h1b, wp, b2, out);
}

// Round 12
// 140.124 us; speedup vs baseline: 8.7409x; 1.1503x over previous
//
#include <hip/hip_runtime.h>
#include <hip/hip_bf16.h>

#define N_NODES 100000
#define N_PAD   100096      // 782 * 128
#define N_EDGES 1600000
#define OUT_CH  40

#define BSHIFT  6           // 64 nodes per bucket
#define BNODES  64
#define NBUCK   1563        // ceil(N_NODES / 64); covers nodes 0..100031
#define CAPB    1408        // edge capacity per bucket (mean 1024, +12 sigma)
#define EPB     32          // edges per thread in bucket_scatter

typedef unsigned short ushort_t;
typedef unsigned int uint_t;
typedef __attribute__((ext_vector_type(8))) short short8;   // 8 bf16 (4 VGPR)
typedef __attribute__((ext_vector_type(4))) float floatx4;  // MFMA C/D

__device__ inline float blo(uint_t u) { union { uint_t i; float f; } t; t.i = u << 16; return t.f; }
__device__ inline float bhi(uint_t u) { union { uint_t i; float f; } t; t.i = u & 0xffff0000u; return t.f; }
__device__ inline ushort_t f2b(float f) {
    __hip_bfloat16 h = __float2bfloat16(f);
    return *reinterpret_cast<ushort_t*>(&h);
}
__device__ inline uint_t pack2(float a, float b) {
    return (uint_t)f2b(a) | ((uint_t)f2b(b) << 16);
}

// ---------------------------------------------------------------------------
// f32 -> bf16 conversion, 8 elems/thread. Block 0 zeroes the bucket cursors.
// ---------------------------------------------------------------------------
__global__ __launch_bounds__(256) void convert_kernel(
    const float* __restrict__ in, ushort_t* __restrict__ out, int n8,
    int* __restrict__ gcur)
{
    if (blockIdx.x == 0) {
        for (int k = threadIdx.x; k < 2048; k += 256) gcur[k] = 0;
    }
    int i = blockIdx.x * 256 + threadIdx.x;
    if (i >= n8) return;
    const float4 a = *reinterpret_cast<const float4*>(in + (size_t)i * 8);
    const float4 b = *reinterpret_cast<const float4*>(in + (size_t)i * 8 + 4);
    uint4 o;
    o.x = pack2(a.x, a.y);
    o.y = pack2(a.z, a.w);
    o.z = pack2(b.x, b.y);
    o.w = pack2(b.z, b.w);
    *reinterpret_cast<uint4*>(out + (size_t)i * 8) = o;
}

// ---------------------------------------------------------------------------
// Weight pack into MFMA B-fragment layout (bf16). Bases (frag units):
// W1l=0, W1r=512, W2l=1024, W2r=1408 (layer-2 cols padded 40->48, zeros).
// ---------------------------------------------------------------------------
__global__ __launch_bounds__(256) void pack_kernel(
    const float* __restrict__ W1l, const float* __restrict__ W1r,
    const float* __restrict__ W2l, const float* __restrict__ W2r,
    uint4* __restrict__ wp)
{
    int i = blockIdx.x * 256 + threadIdx.x;
    if (i >= 1792) return;
    const float* W; int NC; int off;
    if (i < 512)       { W = W1l; NC = 64; off = i; }
    else if (i < 1024) { W = W1r; NC = 64; off = i - 512; }
    else if (i < 1408) { W = W2l; NC = 40; off = i - 1024; }
    else               { W = W2r; NC = 40; off = i - 1408; }
    int l   = off & 63;
    int kc  = (off >> 6) & 1;
    int nt  = off >> 7;
    int k0  = kc * 32 + ((l >> 4) * 8);
    int col = nt * 16 + (l & 15);
    float v[8];
#pragma unroll
    for (int j = 0; j < 8; ++j)
        v[j] = (col < NC) ? W[(k0 + j) * NC + col] : 0.0f;
    uint4 o;
    o.x = pack2(v[0], v[1]);
    o.y = pack2(v[2], v[3]);
    o.z = pack2(v[4], v[5]);
    o.w = pack2(v[6], v[7]);
    wp[i] = o;
}

// ---------------------------------------------------------------------------
// Partition edges into NBUCK dst-range buckets. Randomness confined to LDS
// histogram atomics; one global atomic per (block,bucket); packed edges:
// src (25b) | local-dst << 25. EPB=32 halves allocator atomics vs 16.
// ---------------------------------------------------------------------------
__global__ __launch_bounds__(256) void bucket_scatter(
    const int* __restrict__ src, const int* __restrict__ dst,
    int* __restrict__ gcur, uint_t* __restrict__ bbuf, int n)
{
    __shared__ int lcnt[NBUCK];
    __shared__ int lbase[NBUCK];
    for (int i = threadIdx.x; i < NBUCK; i += 256) lcnt[i] = 0;
    __syncthreads();

    int e0 = blockIdx.x * (256 * EPB) + threadIdx.x;
    int b[EPB], lp[EPB], s[EPB];
#pragma unroll
    for (int u = 0; u < EPB; ++u) {
        int e = e0 + u * 256;
        if (e < n) {
            int d = dst[e];
            s[u] = src[e];
            b[u] = d >> BSHIFT;
            lp[u] = atomicAdd(&lcnt[b[u]], 1);        // pos fits 24 bits
            lp[u] |= (d & (BNODES - 1)) << 24;        // local node in bits 24..29
        } else {
            b[u] = -1;
        }
    }
    __syncthreads();
    for (int i = threadIdx.x; i < NBUCK; i += 256) {
        int c = lcnt[i];
        lbase[i] = (c > 0) ? atomicAdd(&gcur[i], c) : 0;
    }
    __syncthreads();
#pragma unroll
    for (int u = 0; u < EPB; ++u) {
        if (b[u] >= 0) {
            int pos = lbase[b[u]] + (lp[u] & 0x00FFFFFF);
            uint_t ldst = ((uint_t)lp[u]) >> 24;
            if (pos < CAPB)
                bbuf[(size_t)b[u] * CAPB + pos] = (uint_t)s[u] | (ldst << 25);
        }
    }
}

// ---------------------------------------------------------------------------
// Fused per-bucket kernel core (512 threads / 8 waves):
//   A) register-held CSR build: each thread holds its <=3 bbuf entries in
//      regs, LDS-histograms ldeg, wave-0 shfl-scan, places into lcsr.
//   B) gather: 8 nodes per wave, 8 rows per VMEM instr (r=lane>>3 row,
//      c=lane&7 16B chunk), up to 32 rows in flight; mean -> swizzled LDS.
//   C) dense via MFMA straight from LDS mean + global self rows.
// ---------------------------------------------------------------------------
__device__ inline void accum8(float* acc, uint4 v) {
    acc[0] += blo(v.x); acc[1] += bhi(v.x);
    acc[2] += blo(v.y); acc[3] += bhi(v.y);
    acc[4] += blo(v.z); acc[5] += bhi(v.z);
    acc[6] += blo(v.w); acc[7] += bhi(v.w);
}

__device__ inline void build_and_gather(
    const ushort_t* __restrict__ feat, const int* __restrict__ gcur,
    const uint_t* __restrict__ bbuf,
    int* lcsr, int* ldeg, int* lstart, int* lcur, ushort_t* lmean)
{
    int b = blockIdx.x, tid = threadIdx.x;
    int wave = tid >> 6, lane = tid & 63;

    if (tid < BNODES) { ldeg[tid] = 0; lcur[tid] = 0; }
    __syncthreads();

    int ne = gcur[b];
    if (ne > CAPB) ne = CAPB;

    // A1: read edges into registers (<=3 each), histogram degrees in LDS
    uint_t pe[3];
    int npe = 0;
    for (int i = tid; i < ne; i += 512) {
        uint_t p = bbuf[(size_t)b * CAPB + i];
        pe[npe++] = p;
        atomicAdd(&ldeg[p >> 25], 1);
    }
    __syncthreads();

    // A2: wave-0 exclusive scan over 64 degree counts
    if (tid < 64) {
        int v = ldeg[tid];
        int incl = v;
#pragma unroll
        for (int off = 1; off < 64; off <<= 1) {
            int t = __shfl_up(incl, off, 64);
            if (tid >= off) incl += t;
        }
        lstart[tid] = incl - v;
    }
    __syncthreads();

    // A3: place register-held edges into compact LDS CSR
    for (int k = 0; k < npe; ++k) {
        uint_t p = pe[k];
        int d = (int)(p >> 25);
        int pos = atomicAdd(&lcur[d], 1);
        lcsr[lstart[d] + pos] = (int)(p & 0x01FFFFFF);
    }
    __syncthreads();

    // B: gather-mean, 8 nodes per wave
    int r = lane >> 3, c = lane & 7;
    for (int ld = wave * 8; ld < wave * 8 + 8; ++ld) {
        int dg   = ldeg[ld];
        int base = lstart[ld];

        float acc[8] = {0, 0, 0, 0, 0, 0, 0, 0};

        int j = 0;
        for (; j + 32 <= dg; j += 32) {
            int s0 = lcsr[base + j + r];
            int s1 = lcsr[base + j + 8 + r];
            int s2 = lcsr[base + j + 16 + r];
            int s3 = lcsr[base + j + 24 + r];
            uint4 v0 = *reinterpret_cast<const uint4*>(feat + (size_t)s0 * 64 + c * 8);
            uint4 v1 = *reinterpret_cast<const uint4*>(feat + (size_t)s1 * 64 + c * 8);
            uint4 v2 = *reinterpret_cast<const uint4*>(feat + (size_t)s2 * 64 + c * 8);
            uint4 v3 = *reinterpret_cast<const uint4*>(feat + (size_t)s3 * 64 + c * 8);
            accum8(acc, v0); accum8(acc, v1); accum8(acc, v2); accum8(acc, v3);
        }
        if (j + 16 <= dg) {
            int s0 = lcsr[base + j + r];
            int s1 = lcsr[base + j + 8 + r];
            uint4 v0 = *reinterpret_cast<const uint4*>(feat + (size_t)s0 * 64 + c * 8);
            uint4 v1 = *reinterpret_cast<const uint4*>(feat + (size_t)s1 * 64 + c * 8);
            accum8(acc, v0); accum8(acc, v1);
            j += 16;
        }
        if (j + 8 <= dg) {
            int s = lcsr[base + j + r];
            uint4 v = *reinterpret_cast<const uint4*>(feat + (size_t)s * 64 + c * 8);
            accum8(acc, v);
            j += 8;
        }
        if (r < dg - j) {
            int s = lcsr[base + j + r];
            uint4 v = *reinterpret_cast<const uint4*>(feat + (size_t)s * 64 + c * 8);
            accum8(acc, v);
        }

#pragma unroll
        for (int i = 0; i < 8; ++i) {
            acc[i] += __shfl_xor(acc[i], 8, 64);
            acc[i] += __shfl_xor(acc[i], 16, 64);
            acc[i] += __shfl_xor(acc[i], 32, 64);
        }

        if (r == 0) {
            float inv = 1.0f / fmaxf((float)dg, 1.0f);
            uint4 o;
            o.x = pack2(acc[0] * inv, acc[1] * inv);
            o.y = pack2(acc[2] * inv, acc[3] * inv);
            o.z = pack2(acc[4] * inv, acc[5] * inv);
            o.w = pack2(acc[6] * inv, acc[7] * inv);
            int slot = c ^ (ld & 7);    // XOR-swizzle 16B chunks vs row
            *reinterpret_cast<uint4*>(&lmean[ld * 64 + slot * 8]) = o;
        }
    }
    __syncthreads();
}

// ---------------------------------------------------------------------------
// Layer 1 fused: build+gather then h1 = relu(mean@W1l + self@W1r + b1).
// Dense: wave w -> M-tile w>>1, nt pair (w&1)*2.
// ---------------------------------------------------------------------------
__global__ __launch_bounds__(512) void agg_dense1(
    const ushort_t* __restrict__ xb, const int* __restrict__ gcur,
    const uint_t* __restrict__ bbuf, const uint4* __restrict__ wp,
    const float* __restrict__ bias, ushort_t* __restrict__ h1b)
{
    __shared__ int lcsr[CAPB];
    __shared__ int ldeg[BNODES];
    __shared__ int lstart[BNODES];
    __shared__ int lcur[BNODES];
    __shared__ ushort_t lmean[BNODES * 64];   // 8 KB

    build_and_gather(xb, gcur, bbuf, lcsr, ldeg, lstart, lcur, lmean);

    int tid = threadIdx.x;
    int wave = tid >> 6, lane = tid & 63;
    int node0 = blockIdx.x << BSHIFT;
    int q = lane >> 4, c16 = lane & 15;
    int mt  = wave >> 1;            // M-tile 0..3
    int nt0 = (wave & 1) * 2;       // nt pair
    int mrow = mt * 16 + c16;

    short8 am0 = *reinterpret_cast<const short8*>(&lmean[mrow * 64 + ((q ^ (mrow & 7)) << 3)]);
    short8 am1 = *reinterpret_cast<const short8*>(&lmean[mrow * 64 + (((q + 4) ^ (mrow & 7)) << 3)]);
    const ushort_t* sr = xb + (size_t)(node0 + mrow) * 64 + q * 8;
    short8 as0 = *reinterpret_cast<const short8*>(sr);
    short8 as1 = *reinterpret_cast<const short8*>(sr + 32);

#pragma unroll
    for (int t = 0; t < 2; ++t) {
        int nt = nt0 + t;
        short8 bl0 = *reinterpret_cast<const short8*>(&wp[nt * 128 + lane]);
        short8 bl1 = *reinterpret_cast<const short8*>(&wp[nt * 128 + 64 + lane]);
        short8 br0 = *reinterpret_cast<const short8*>(&wp[512 + nt * 128 + lane]);
        short8 br1 = *reinterpret_cast<const short8*>(&wp[512 + nt * 128 + 64 + lane]);
        float bv = bias[nt * 16 + c16];
        floatx4 a = (floatx4){bv, bv, bv, bv};
        a = __builtin_amdgcn_mfma_f32_16x16x32_bf16(am0, bl0, a, 0, 0, 0);
        a = __builtin_amdgcn_mfma_f32_16x16x32_bf16(am1, bl1, a, 0, 0, 0);
        a = __builtin_amdgcn_mfma_f32_16x16x32_bf16(as0, br0, a, 0, 0, 0);
        a = __builtin_amdgcn_mfma_f32_16x16x32_bf16(as1, br1, a, 0, 0, 0);
#pragma unroll
        for (int rr = 0; rr < 4; ++rr) {
            int node = node0 + mt * 16 + q * 4 + rr;
            h1b[(size_t)node * 64 + nt * 16 + c16] = f2b(fmaxf(a[rr], 0.0f));
        }
    }
}

// ---------------------------------------------------------------------------
// Layer 2 fused: build+gather(h1) then MFMA + log_softmax -> f32 out.
// Dense: waves 0..3 each own one M-tile (all 3 nt; softmax needs the row).
// ---------------------------------------------------------------------------
__global__ __launch_bounds__(512) void agg_dense2(
    const ushort_t* __restrict__ h1b, const int* __restrict__ gcur,
    const uint_t* __restrict__ bbuf, const uint4* __restrict__ wp,
    const float* __restrict__ bias, float* __restrict__ out)
{
    __shared__ int lcsr[CAPB];
    __shared__ int ldeg[BNODES];
    __shared__ int lstart[BNODES];
    __shared__ int lcur[BNODES];
    __shared__ ushort_t lmean[BNODES * 64];

    build_and_gather(h1b, gcur, bbuf, lcsr, ldeg, lstart, lcur, lmean);

    int tid = threadIdx.x;
    int wave = tid >> 6, lane = tid & 63;
    if (wave >= 4) return;

    int node0 = blockIdx.x << BSHIFT;
    int q = lane >> 4, c16 = lane & 15;
    int mt = wave;
    int mrow = mt * 16 + c16;
    bool v2ok = c16 < 8;    // tile 2 real cols: 32..39

    short8 am0 = *reinterpret_cast<const short8*>(&lmean[mrow * 64 + ((q ^ (mrow & 7)) << 3)]);
    short8 am1 = *reinterpret_cast<const short8*>(&lmean[mrow * 64 + (((q + 4) ^ (mrow & 7)) << 3)]);
    const ushort_t* sr = h1b + (size_t)(node0 + mrow) * 64 + q * 8;
    short8 as0 = *reinterpret_cast<const short8*>(sr);
    short8 as1 = *reinterpret_cast<const short8*>(sr + 32);

    floatx4 av[3];
#pragma unroll
    for (int nt = 0; nt < 3; ++nt) {
        short8 bl0 = *reinterpret_cast<const short8*>(&wp[1024 + nt * 128 + lane]);
        short8 bl1 = *reinterpret_cast<const short8*>(&wp[1024 + nt * 128 + 64 + lane]);
        short8 br0 = *reinterpret_cast<const short8*>(&wp[1408 + nt * 128 + lane]);
        short8 br1 = *reinterpret_cast<const short8*>(&wp[1408 + nt * 128 + 64 + lane]);
        int col = nt * 16 + c16;
        float bv = (col < OUT_CH) ? bias[col] : 0.0f;
        floatx4 a = (floatx4){bv, bv, bv, bv};
        a = __builtin_amdgcn_mfma_f32_16x16x32_bf16(am0, bl0, a, 0, 0, 0);
        a = __builtin_amdgcn_mfma_f32_16x16x32_bf16(am1, bl1, a, 0, 0, 0);
        a = __builtin_amdgcn_mfma_f32_16x16x32_bf16(as0, br0, a, 0, 0, 0);
        a = __builtin_amdgcn_mfma_f32_16x16x32_bf16(as1, br1, a, 0, 0, 0);
        av[nt] = a;
    }

    // fused log_softmax per node; row lives in the 16-lane col group
    // (shfl_xor 1,2,4,8 stays within the group; q fixed).
#pragma unroll
    for (int rr = 0; rr < 4; ++rr) {
        float v0 = av[0][rr];
        float v1 = av[1][rr];
        float v2 = av[2][rr];
        float mx = fmaxf(fmaxf(v0, v1), v2ok ? v2 : -1e30f);
        mx = fmaxf(mx, __shfl_xor(mx, 1, 64));
        mx = fmaxf(mx, __shfl_xor(mx, 2, 64));
        mx = fmaxf(mx, __shfl_xor(mx, 4, 64));
        mx = fmaxf(mx, __shfl_xor(mx, 8, 64));
        float e = __expf(v0 - mx) + __expf(v1 - mx) + (v2ok ? __expf(v2 - mx) : 0.0f);
        e += __shfl_xor(e, 1, 64);
        e += __shfl_xor(e, 2, 64);
        e += __shfl_xor(e, 4, 64);
        e += __shfl_xor(e, 8, 64);
        float ls = __logf(e);
        int node = node0 + mt * 16 + q * 4 + rr;
        if (node < N_NODES) {
            out[(size_t)node * OUT_CH + c16]      = v0 - mx - ls;
            out[(size_t)node * OUT_CH + 16 + c16] = v1 - mx - ls;
            if (v2ok)
                out[(size_t)node * OUT_CH + 32 + c16] = v2 - mx - ls;
        }
    }
}

extern "C" void kernel_launch(void* const* d_in, const int* in_sizes, int n_in,
                              void* d_out, int out_size, void* d_ws, size_t ws_size,
                              hipStream_t stream)
{
    const float* x   = (const float*)d_in[0];
    const int*   ei  = (const int*)d_in[1];     // (2, N_EDGES) int32
    const float* W1l = (const float*)d_in[2];
    const float* W1r = (const float*)d_in[3];
    const float* b1  = (const float*)d_in[4];
    const float* W2l = (const float*)d_in[5];
    const float* W2r = (const float*)d_in[6];
    const float* b2  = (const float*)d_in[7];
    float* out = (float*)d_out;

    const int* src = ei;
    const int* dst = ei + N_EDGES;

    // workspace layout
    int* gcur       = (int*)d_ws;                         // [2048] bucket cursors
    uint4* wp       = (uint4*)(gcur + 2048);              // [1792] frags, 28KB
    uint_t* bbuf    = (uint_t*)(wp + 1792);               // [NBUCK*CAPB] packed edges ~8.8MB
    ushort_t* xb    = (ushort_t*)(bbuf + (size_t)NBUCK * CAPB);  // [N_PAD*64] bf16
    ushort_t* h1b   = xb + (size_t)N_PAD * 64;            // [N_PAD*64] bf16
    // total ~= 0.04 + 8.8 + 25.6 MB ~= 34.5 MB

    const int n8 = N_NODES * 64 / 8;

    convert_kernel<<<(n8 + 255) / 256, 256, 0, stream>>>(x, xb, n8, gcur);
    pack_kernel<<<7, 256, 0, stream>>>(W1l, W1r, W2l, W2r, wp);

    const int sblocks = (N_EDGES + 256 * EPB - 1) / (256 * EPB);
    bucket_scatter<<<sblocks, 256, 0, stream>>>(src, dst, gcur, bbuf, N_EDGES);

    agg_dense1<<<NBUCK, 512, 0, stream>>>(xb, gcur, bbuf, wp, b1, h1b);
    agg_dense2<<<NBUCK, 512, 0, stream>>>(h1b, gcur, bbuf, wp, b2, out);
}